// Round 8
// baseline (146.724 us; speedup 1.0000x reference)
//
#include <hip/hip_runtime.h>
#include <hip/hip_bf16.h>

// Problem constants
#define BB 2
#define TT 2048
#define DD 512
#define HH 8
#define DH 64
#define INNER 512
#define MAXLAG 5

typedef __attribute__((ext_vector_type(8))) short short8;
typedef __attribute__((ext_vector_type(4))) float floatx4;
typedef unsigned short ushort_t;

__device__ inline unsigned short f2bf(float f) {
    unsigned u = __float_as_uint(f);
    unsigned r = (u + 0x7FFFu + ((u >> 16) & 1u)) >> 16;
    return (unsigned short)r;
}
__device__ inline float bf2f(unsigned short u) {
    return __uint_as_float(((unsigned)u) << 16);
}

// Async global->LDS 16B (global_load_lds_dwordx4). LDS dest is wave-uniform
// base + lane*16 (lane-linear). LDS swizzles are applied by pre-swizzling
// the per-lane SOURCE address (m173 pattern).
__device__ __forceinline__ void gload16(ushort_t* lds, const ushort_t* g) {
    __builtin_amdgcn_global_load_lds(
        (const __attribute__((address_space(1))) void*)g,
        (__attribute__((address_space(3))) void*)lds, 16, 0, 0);
}

// ---------------------------------------------------------------------------
// Fused convert: blocks [0,1024): x -> bf16; blocks [1024,2048): weight
// transpose+convert via 32x32 LDS tile. Wq/Wk/Wv land in ONE fused buffer
// wqkvt[1536][512]; Wo^T separate.
// ---------------------------------------------------------------------------
__global__ __launch_bounds__(256)
void cvt_kernel(const float* __restrict__ x,
                const float* __restrict__ wq, const float* __restrict__ wk,
                const float* __restrict__ wv, const float* __restrict__ wo,
                ushort_t* __restrict__ xb,
                ushort_t* __restrict__ wqkvt, ushort_t* __restrict__ wot)
{
    __shared__ float T[32][33];
    const int bid = blockIdx.x;
    if (bid < 1024) {
        int off = (bid * 256 + threadIdx.x) * 8;
        float4 a = *(const float4*)&x[off];
        float4 b = *(const float4*)&x[off + 4];
        ushort_t t[8];
        t[0] = f2bf(a.x); t[1] = f2bf(a.y); t[2] = f2bf(a.z); t[3] = f2bf(a.w);
        t[4] = f2bf(b.x); t[5] = f2bf(b.y); t[6] = f2bf(b.z); t[7] = f2bf(b.w);
        *(uint4*)&xb[off] = *(const uint4*)t;
        return;
    }
    const int r = bid - 1024;
    const int z = r >> 8;
    const int tile = r & 255;
    const float* s = (z == 0) ? wq : (z == 1) ? wk : (z == 2) ? wv : wo;
    ushort_t*    d = (z < 3) ? (wqkvt + (size_t)z * 512 * 512) : wot;
    const int k0 = (tile & 15) * 32;
    const int n0 = (tile >> 4) * 32;
    {
        const int kk = threadIdx.x >> 3;
        const int n4 = (threadIdx.x & 7) * 4;
        float4 v = *(const float4*)&s[(size_t)(k0 + kk) * 512 + n0 + n4];
        T[kk][n4 + 0] = v.x; T[kk][n4 + 1] = v.y;
        T[kk][n4 + 2] = v.z; T[kk][n4 + 3] = v.w;
    }
    __syncthreads();
    {
        const int nn = threadIdx.x >> 3;
        const int k4 = (threadIdx.x & 7) * 4;
        ushort4 o;
        o.x = f2bf(T[k4 + 0][nn]); o.y = f2bf(T[k4 + 1][nn]);
        o.z = f2bf(T[k4 + 2][nn]); o.w = f2bf(T[k4 + 3][nn]);
        *(ushort4*)&d[(size_t)(n0 + nn) * 512 + k0 + k4] = o;
    }
}

// ---------------------------------------------------------------------------
// QKV GEMM (R7 version, proven): 128x64 tile, BK=64, gload_lds(16B),
// chunk-rotated LDS (conflict-free frag reads), fused N=1536.
// ---------------------------------------------------------------------------
#define QM 128
#define QN 64
#define QKS 64

__global__ __launch_bounds__(256)
void gemm_qkv(const ushort_t* __restrict__ A, const ushort_t* __restrict__ Bw,
              ushort_t* __restrict__ q, ushort_t* __restrict__ k,
              ushort_t* __restrict__ vt)
{
    __shared__ ushort_t As[QM * QKS];   // 16 KB: granules 0..1023
    __shared__ ushort_t Bs[QN * QKS];   // 8 KB:  granules 0..511

    const int tid  = threadIdx.x;
    const int wave = tid >> 6;
    const int lane = tid & 63;
    const int quad = lane >> 4;
    const int l15  = lane & 15;
    const int wr   = wave >> 1;
    const int wc   = wave & 1;
    const int bm   = blockIdx.y * QM;
    const int bn   = blockIdx.x * QN;

    const int lr = lane >> 3;
    const int lc = lane & 7;

    const ushort_t* ap[4];
#pragma unroll
    for (int j = 0; j < 4; ++j) {
        const int row = wave * 32 + j * 8 + lr;
        const int c   = (lc - row) & 7;
        ap[j] = &A[(size_t)(bm + row) * DD + c * 8];
    }
    const ushort_t* bp[2];
#pragma unroll
    for (int j = 0; j < 2; ++j) {
        const int row = wave * 16 + j * 8 + lr;
        const int c   = (lc - row) & 7;
        bp[j] = &Bw[(size_t)(bn + row) * DD + c * 8];
    }
    ushort_t* lA0 = &As[(size_t)(wave * 256 +   0) * 8];
    ushort_t* lA1 = &As[(size_t)(wave * 256 +  64) * 8];
    ushort_t* lA2 = &As[(size_t)(wave * 256 + 128) * 8];
    ushort_t* lA3 = &As[(size_t)(wave * 256 + 192) * 8];
    ushort_t* lB0 = &Bs[(size_t)(wave * 128 +  0) * 8];
    ushort_t* lB1 = &Bs[(size_t)(wave * 128 + 64) * 8];

    floatx4 acc[4][2];
#pragma unroll
    for (int i = 0; i < 4; ++i)
#pragma unroll
        for (int j = 0; j < 2; ++j) acc[i][j] = (floatx4){0.f, 0.f, 0.f, 0.f};

#pragma unroll
    for (int k0 = 0; k0 < DD; k0 += QKS) {
        __syncthreads();
        gload16(lA0, ap[0] + k0);
        gload16(lA1, ap[1] + k0);
        gload16(lA2, ap[2] + k0);
        gload16(lA3, ap[3] + k0);
        gload16(lB0, bp[0] + k0);
        gload16(lB1, bp[1] + k0);
        __syncthreads();

#pragma unroll
        for (int kk = 0; kk < 2; ++kk) {
            short8 af[4], bfr[2];
#pragma unroll
            for (int mt = 0; mt < 4; ++mt) {
                const int row = wr * 64 + mt * 16 + l15;
                af[mt] = *(const short8*)
                    &As[((row << 3) + ((kk * 4 + quad + row) & 7)) * 8];
            }
#pragma unroll
            for (int nt = 0; nt < 2; ++nt) {
                const int row = wc * 32 + nt * 16 + l15;
                bfr[nt] = *(const short8*)
                    &Bs[((row << 3) + ((kk * 4 + quad + row) & 7)) * 8];
            }
#pragma unroll
            for (int mt = 0; mt < 4; ++mt)
#pragma unroll
                for (int nt = 0; nt < 2; ++nt)
                    acc[mt][nt] = __builtin_amdgcn_mfma_f32_16x16x32_bf16(
                        af[mt], bfr[nt], acc[mt][nt], 0, 0, 0);
        }
    }

    const int z = bn >> 9;   // 0=Q, 1=K, 2=V (uniform per block)
    if (z == 2) {
#pragma unroll
        for (int mt = 0; mt < 4; ++mt) {
            const int m0 = bm + wr * 64 + mt * 16 + quad * 4;
            const int b  = m0 >> 11;
            const int t0 = m0 & 2047;
#pragma unroll
            for (int nt = 0; nt < 2; ++nt) {
                const int n  = bn + wc * 32 + nt * 16 + l15 - 1024;
                const int h  = n >> 6, dd = n & 63;
                ushort4 o;
                o.x = f2bf(acc[mt][nt][0]); o.y = f2bf(acc[mt][nt][1]);
                o.z = f2bf(acc[mt][nt][2]); o.w = f2bf(acc[mt][nt][3]);
                *(ushort4*)&vt[((size_t)((b * 8 + h) * 64 + dd)) * 2048 + t0] = o;
            }
        }
        return;
    }
    ushort_t* O = (z == 0) ? q : k;
    const int nb = bn - z * 512;
#pragma unroll
    for (int mt = 0; mt < 4; ++mt) {
#pragma unroll
        for (int nt = 0; nt < 2; ++nt) {
            const int n = nb + wc * 32 + nt * 16 + l15;
#pragma unroll
            for (int reg = 0; reg < 4; ++reg) {
                const int m = bm + wr * 64 + mt * 16 + quad * 4 + reg;
                O[(size_t)m * 512 + n] = f2bf(acc[mt][nt][reg]);
            }
        }
    }
}

// ---------------------------------------------------------------------------
// Projection GEMM (R7 version, proven): 64x64, BK=64, gload_lds staging,
// chunk-rotated LDS layout.
// ---------------------------------------------------------------------------
__global__ __launch_bounds__(256)
void gemm_proj(const ushort_t* __restrict__ A, const ushort_t* __restrict__ Bw,
               float* __restrict__ O, const float* __restrict__ bias)
{
    __shared__ ushort_t As[64 * 64];
    __shared__ ushort_t Bs[64 * 64];

    const int tid  = threadIdx.x;
    const int wave = tid >> 6;
    const int lane = tid & 63;
    const int quad = lane >> 4;
    const int l15  = lane & 15;
    const int wr   = wave >> 1;
    const int wc   = wave & 1;
    const int bm   = blockIdx.y * 64;
    const int bn   = blockIdx.x * 64;

    const int lr = lane >> 3;
    const int lc = lane & 7;

    const ushort_t* ap[2];
    const ushort_t* bp[2];
#pragma unroll
    for (int j = 0; j < 2; ++j) {
        const int row = wave * 16 + j * 8 + lr;
        const int c   = (lc - row) & 7;
        ap[j] = &A[(size_t)(bm + row) * INNER + c * 8];
        bp[j] = &Bw[(size_t)(bn + row) * INNER + c * 8];
    }
    ushort_t* lA0 = &As[(size_t)(wave * 128 +  0) * 8];
    ushort_t* lA1 = &As[(size_t)(wave * 128 + 64) * 8];
    ushort_t* lB0 = &Bs[(size_t)(wave * 128 +  0) * 8];
    ushort_t* lB1 = &Bs[(size_t)(wave * 128 + 64) * 8];

    floatx4 acc[2][2];
#pragma unroll
    for (int i = 0; i < 2; ++i)
#pragma unroll
        for (int j = 0; j < 2; ++j) acc[i][j] = (floatx4){0.f, 0.f, 0.f, 0.f};

#pragma unroll
    for (int k0 = 0; k0 < INNER; k0 += 64) {
        __syncthreads();
        gload16(lA0, ap[0] + k0);
        gload16(lA1, ap[1] + k0);
        gload16(lB0, bp[0] + k0);
        gload16(lB1, bp[1] + k0);
        __syncthreads();

#pragma unroll
        for (int kk = 0; kk < 2; ++kk) {
            short8 af[2], bfr[2];
#pragma unroll
            for (int mt = 0; mt < 2; ++mt) {
                const int row = wr * 32 + mt * 16 + l15;
                af[mt] = *(const short8*)
                    &As[((row << 3) + ((kk * 4 + quad + row) & 7)) * 8];
            }
#pragma unroll
            for (int nt = 0; nt < 2; ++nt) {
                const int row = wc * 32 + nt * 16 + l15;
                bfr[nt] = *(const short8*)
                    &Bs[((row << 3) + ((kk * 4 + quad + row) & 7)) * 8];
            }
#pragma unroll
            for (int mt = 0; mt < 2; ++mt)
#pragma unroll
                for (int nt = 0; nt < 2; ++nt)
                    acc[mt][nt] = __builtin_amdgcn_mfma_f32_16x16x32_bf16(
                        af[mt], bfr[nt], acc[mt][nt], 0, 0, 0);
        }
    }

    float bv[2];
#pragma unroll
    for (int nt = 0; nt < 2; ++nt)
        bv[nt] = bias[bn + wc * 32 + nt * 16 + l15];
#pragma unroll
    for (int mt = 0; mt < 2; ++mt) {
#pragma unroll
        for (int nt = 0; nt < 2; ++nt) {
            const int n = bn + wc * 32 + nt * 16 + l15;
#pragma unroll
            for (int reg = 0; reg < 4; ++reg) {
                const int m = bm + wr * 32 + mt * 16 + quad * 4 + reg;
                O[(size_t)m * 512 + n] = acc[mt][nt][reg] + bv[nt];
            }
        }
    }
}

// ---------------------------------------------------------------------------
// MFMA flash attention, chunked K-split (chunk=8, heavy-first). NEW this
// round: V is NOT staged in LDS (m169 pattern: per-(b,h) V^T slice = 256KB,
// fully L2-resident; 16 bh * 256KB = 4MB << 32MB L2). V-frags are loaded
// per-cb directly from vt (16B contiguous per lane), issued at the TOP of
// each iteration so they complete under QK^T + softmax. K staging, Pl
// roundtrip, decode, epilogues: R7 verbatim. LDS 26KB -> 17.4KB.
// ---------------------------------------------------------------------------
#define PAD 72
#define MFIX 10.0f

__global__ __launch_bounds__(256)
void attn_mfma(const ushort_t* __restrict__ Qg,
               const ushort_t* __restrict__ Kg,
               const ushort_t* __restrict__ Vtg,
               const float* __restrict__ lagw,
               ushort_t* __restrict__ Opart,
               float* __restrict__ Lpart,
               ushort_t* __restrict__ ao)
{
    __shared__ ushort_t Ks[64 * 8 * 8];
    __shared__ ushort_t Pl[4][16][PAD];

    const int tid  = threadIdx.x;
    const int wave = tid >> 6;
    const int lane = tid & 63;
    const int quad = lane >> 4;
    const int l15  = lane & 15;

    // heavy-first chunk decode: f = rank*16 + bh; rank rr in [0,80)
    const int f  = blockIdx.x;           // 0..1279
    const int rr = f >> 4;
    const int bh = f & 15;
    int qt, ci;
    if (rr < 32)      { qt = 31 - (rr >> 2); ci = rr & 3; }
    else if (rr < 56) { const int t = rr - 32; qt = 23 - t / 3; ci = t % 3; }
    else if (rr < 72) { const int t = rr - 56; qt = 15 - (t >> 1); ci = t & 1; }
    else              { qt = 79 - rr; ci = 0; }
    const int lo = ci * 8;
    const int hi = min(lo + 8, qt + 1);
    const int nch = (qt >> 3) + 1;

    const int b  = bh >> 3;
    const int h  = bh & 7;
    const int i0 = qt * 64;

    float lagb[MAXLAG + 1];
    {
        float mx = -1e30f;
#pragma unroll
        for (int l = 0; l <= MAXLAG; ++l) {
            lagb[l] = lagw[h * (MAXLAG + 1) + l];
            mx = fmaxf(mx, lagb[l]);
        }
        float s = 0.f;
#pragma unroll
        for (int l = 0; l <= MAXLAG; ++l) { lagb[l] = __expf(lagb[l] - mx); s += lagb[l]; }
        float inv = 1.f / s;
#pragma unroll
        for (int l = 0; l <= MAXLAG; ++l) lagb[l] = lagb[l] * inv - MFIX;
    }
    const float c1  = 0.125f;
    const float c2f = lagb[MAXLAG];

    short8 qf0, qf1;
    {
        const ushort_t* qbase =
            Qg + ((size_t)(b * TT + i0 + wave * 16 + l15)) * INNER + h * DH;
        qf0 = *(const short8*)(qbase + quad * 8);
        qf1 = *(const short8*)(qbase + 32 + quad * 8);
    }

    floatx4 oacc[4];
    float lsum[4] = {0.f, 0.f, 0.f, 0.f};
#pragma unroll
    for (int cb = 0; cb < 4; ++cb) oacc[cb] = (floatx4){0.f, 0.f, 0.f, 0.f};

    const int ibase = i0 + wave * 16 + quad * 4;

    // K staging only (V dropped from LDS)
    const int srow = tid >> 3;
    const int sc   = tid & 7;
    const ushort_t* Kp0 = Kg + ((size_t)(b * TT) + srow) * INNER + h * DH + sc * 8;
    const ushort_t* Kp1 = Kp0 + (size_t)32 * INNER;
    const int slot = (sc + srow) & 7;
    const int kdst0 = ((srow << 3) + slot) << 3;
    const int kdst1 = (((srow + 32) << 3) + slot) << 3;

    // per-cb V row base: vt[(bh*64 + cb*16 + l15)][...], 16B contiguous reads
    const ushort_t* vrow[4];
#pragma unroll
    for (int cb = 0; cb < 4; ++cb)
        vrow[cb] = Vtg + ((size_t)(bh * 64 + cb * 16 + l15)) * 2048;

    uint4 pk0, pk1;
    {
        const size_t koff = (size_t)(lo * 64) * INNER;
        pk0 = *(const uint4*)(Kp0 + koff);
        pk1 = *(const uint4*)(Kp1 + koff);
    }

    for (int kt = lo; kt < hi; ++kt) {
        const int j0 = kt * 64;

        // V-frag loads issued FIRST: independent of LDS staging; complete
        // under QK^T + softmax (L2-resident).
        short8 vf0[4], vf1[4];
#pragma unroll
        for (int cb = 0; cb < 4; ++cb) {
            vf0[cb] = *(const short8*)(vrow[cb] + j0 + quad * 8);
            vf1[cb] = *(const short8*)(vrow[cb] + j0 + 32 + quad * 8);
        }

        __syncthreads();
        *(uint4*)&Ks[kdst0] = pk0;
        *(uint4*)&Ks[kdst1] = pk1;
        if (kt + 1 < hi) {
            const size_t koff = (size_t)((kt + 1) * 64) * INNER;
            pk0 = *(const uint4*)(Kp0 + koff);
            pk1 = *(const uint4*)(Kp1 + koff);
        }
        __syncthreads();

        floatx4 sacc[4];
#pragma unroll
        for (int cb = 0; cb < 4; ++cb) {
            const int key = cb * 16 + l15;
            short8 kf0 = *(const short8*)&Ks[((key << 3) + ((quad + key) & 7)) << 3];
            short8 kf1 = *(const short8*)&Ks[((key << 3) + ((quad + 4 + key) & 7)) << 3];
            floatx4 zf = (floatx4){0.f, 0.f, 0.f, 0.f};
            zf = __builtin_amdgcn_mfma_f32_16x16x32_bf16(qf0, kf0, zf, 0, 0, 0);
            zf = __builtin_amdgcn_mfma_f32_16x16x32_bf16(qf1, kf1, zf, 0, 0, 0);
            sacc[cb] = zf;
        }

        float p[4][4];
        if (i0 + wave * 16 - (j0 + 63) >= MAXLAG) {
#pragma unroll
            for (int cb = 0; cb < 4; ++cb)
#pragma unroll
                for (int reg = 0; reg < 4; ++reg)
                    p[cb][reg] = __expf(fmaf(sacc[cb][reg], c1, c2f));
        } else {
#pragma unroll
            for (int cb = 0; cb < 4; ++cb) {
                const int j = j0 + cb * 16 + l15;
#pragma unroll
                for (int reg = 0; reg < 4; ++reg) {
                    const int lag = (ibase + reg) - j;
                    float bias = (lag <= 0) ? lagb[0]
                               : (lag == 1) ? lagb[1]
                               : (lag == 2) ? lagb[2]
                               : (lag == 3) ? lagb[3]
                               : (lag == 4) ? lagb[4] : lagb[5];
                    float e = __expf(fmaf(sacc[cb][reg], c1, bias));
                    p[cb][reg] = (lag < 0) ? 0.f : e;
                }
            }
        }
#pragma unroll
        for (int cb = 0; cb < 4; ++cb)
#pragma unroll
            for (int reg = 0; reg < 4; ++reg)
                lsum[reg] += p[cb][reg];

#pragma unroll
        for (int cb = 0; cb < 4; ++cb)
#pragma unroll
            for (int reg = 0; reg < 4; ++reg)
                Pl[wave][quad * 4 + reg][cb * 16 + l15] = f2bf(p[cb][reg]);

        short8 pf0 = *(const short8*)&Pl[wave][l15][quad * 8];
        short8 pf1 = *(const short8*)&Pl[wave][l15][32 + quad * 8];

#pragma unroll
        for (int cb = 0; cb < 4; ++cb) {
            oacc[cb] = __builtin_amdgcn_mfma_f32_16x16x32_bf16(pf0, vf0[cb], oacc[cb], 0, 0, 0);
            oacc[cb] = __builtin_amdgcn_mfma_f32_16x16x32_bf16(pf1, vf1[cb], oacc[cb], 0, 0, 0);
        }
    }

#pragma unroll
    for (int reg = 0; reg < 4; ++reg) {
        lsum[reg] += __shfl_xor(lsum[reg], 1);
        lsum[reg] += __shfl_xor(lsum[reg], 2);
        lsum[reg] += __shfl_xor(lsum[reg], 4);
        lsum[reg] += __shfl_xor(lsum[reg], 8);
    }

    if (nch == 1) {
        // single-chunk group (qt<8): normalize + write final output directly
#pragma unroll
        for (int reg = 0; reg < 4; ++reg) {
            const int row = ibase + reg;
            const float inv = 1.f / lsum[reg];
            ushort_t* dst = &ao[((size_t)(b * TT + row)) * INNER + h * DH];
#pragma unroll
            for (int cb = 0; cb < 4; ++cb)
                dst[cb * 16 + l15] = f2bf(oacc[cb][reg] * inv);
        }
        return;
    }

    // multi-chunk: write unnormalized partials into slot ci
#pragma unroll
    for (int reg = 0; reg < 4; ++reg) {
        const int row = ibase + reg;
        const size_t obase = ((size_t)(ci * 16 + bh) * TT + row) * 64;
#pragma unroll
        for (int cb = 0; cb < 4; ++cb)
            Opart[obase + cb * 16 + l15] = f2bf(oacc[cb][reg]);
        if (l15 == 0)
            Lpart[(size_t)(ci * 16 + bh) * TT + row] = lsum[reg];
    }
}

// ---------------------------------------------------------------------------
// Combine up to 4 chunk partials -> ao bf16 [b*T+i][h*64+d], rows i>=512
// only (qt>=8 <=> nch>=2; qt<8 rows were written inline by attn_mfma).
// ---------------------------------------------------------------------------
#define CMB_ROWS (TT - 512)
#define CMB_UNITS (16 * CMB_ROWS * 16)

__global__ __launch_bounds__(256)
void combine_kernel(const ushort_t* __restrict__ Opart,
                    const float* __restrict__ Lpart,
                    ushort_t* __restrict__ ao)
{
    int u = blockIdx.x * 256 + threadIdx.x;
    const int bh  = u / (CMB_ROWS * 16);
    const int rem = u - bh * (CMB_ROWS * 16);
    const int i   = 512 + (rem >> 4);
    const int d   = (rem & 15) * 4;
    const int b   = bh >> 3;
    const int h   = bh & 7;
    const int nch = ((i >> 6) >> 3) + 1;

    float s0 = 0.f, s1 = 0.f, s2 = 0.f, s3 = 0.f, l = 0.f;
    for (int ci = 0; ci < nch; ++ci) {
        const size_t p = ((size_t)(ci * 16 + bh) * TT + i) * 64 + d;
        ushort4 a = *(const ushort4*)&Opart[p];
        s0 += bf2f(a.x); s1 += bf2f(a.y); s2 += bf2f(a.z); s3 += bf2f(a.w);
        l  += Lpart[(size_t)(ci * 16 + bh) * TT + i];
    }
    const float inv = 1.f / l;
    ushort4 o;
    o.x = f2bf(s0 * inv);
    o.y = f2bf(s1 * inv);
    o.z = f2bf(s2 * inv);
    o.w = f2bf(s3 * inv);
    *(ushort4*)&ao[((size_t)(b * TT + i)) * INNER + h * DH + d] = o;
}

// ---------------------------------------------------------------------------
extern "C" void kernel_launch(void* const* d_in, const int* in_sizes, int n_in,
                              void* d_out, int out_size, void* d_ws, size_t ws_size,
                              hipStream_t stream)
{
    const float* x  = (const float*)d_in[0];
    const float* Wq = (const float*)d_in[1];
    const float* Wk = (const float*)d_in[2];
    const float* Wv = (const float*)d_in[3];
    const float* Wo = (const float*)d_in[4];
    const float* bo = (const float*)d_in[5];
    const float* lw = (const float*)d_in[6];
    float* out = (float*)d_out;

    const size_t SZ  = (size_t)BB * TT * INNER;  // 2M elements
    const size_t NWE = (size_t)DD * INNER;       // 256K per weight
    ushort_t* xb    = (ushort_t*)d_ws;
    ushort_t* wqkvt = xb + SZ;                   // fused [1536][512]
    ushort_t* wot   = wqkvt + 3 * NWE;
    ushort_t* q     = wot + NWE;
    ushort_t* k     = q + SZ;
    ushort_t* vt    = k + SZ;                    // V TRANSPOSED [bh][d][t]
    ushort_t* opart = vt + SZ;                   // 4 slots * 16*TT*64
    float*    lpart = (float*)(opart + 4 * (size_t)16 * TT * 64);
    ushort_t* ao    = xb;                        // alias: xb dead after QKV

    cvt_kernel<<<2048, 256, 0, stream>>>(x, Wq, Wk, Wv, Wo, xb, wqkvt, wot);

    dim3 gQKV(3 * INNER / QN, (BB * TT) / QM);   // (24, 32) = 768 blocks
    gemm_qkv<<<gQKV, 256, 0, stream>>>(xb, wqkvt, q, k, vt);

    attn_mfma<<<1280, 256, 0, stream>>>(q, k, vt, lw, opart, lpart, ao);

    combine_kernel<<<CMB_UNITS / 256, 256, 0, stream>>>(opart, lpart, ao);

    dim3 gPRJ(DD / 64, (BB * TT) / 64);          // (8, 64) = 512 blocks
    gemm_proj<<<gPRJ, 256, 0, stream>>>(ao, wot, out, bo);
}

// Round 10
// 124.722 us; speedup vs baseline: 1.1764x; 1.1764x over previous
//
#include <hip/hip_runtime.h>
#include <hip/hip_bf16.h>

// Problem constants
#define BB 2
#define TT 2048
#define DD 512
#define HH 8
#define DH 64
#define INNER 512
#define MAXLAG 5

typedef __attribute__((ext_vector_type(8))) short short8;
typedef __attribute__((ext_vector_type(4))) float floatx4;
typedef unsigned short ushort_t;

__device__ inline unsigned short f2bf(float f) {
    unsigned u = __float_as_uint(f);
    unsigned r = (u + 0x7FFFu + ((u >> 16) & 1u)) >> 16;
    return (unsigned short)r;
}
__device__ inline float bf2f(unsigned short u) {
    return __uint_as_float(((unsigned)u) << 16);
}

// Async global->LDS 16B (global_load_lds_dwordx4). LDS dest is wave-uniform
// base + lane*16 (lane-linear). LDS swizzles are applied by pre-swizzling
// the per-lane SOURCE address (m173 pattern).
__device__ __forceinline__ void gload16(ushort_t* lds, const ushort_t* g) {
    __builtin_amdgcn_global_load_lds(
        (const __attribute__((address_space(1))) void*)g,
        (__attribute__((address_space(3))) void*)lds, 16, 0, 0);
}

// ---------------------------------------------------------------------------
// Fused convert: blocks [0,1024): x -> bf16; blocks [1024,2048): weight
// transpose+convert via 32x32 LDS tile. Wq/Wk/Wv land in ONE fused buffer
// wqkvt[1536][512]; Wo^T separate.
// ---------------------------------------------------------------------------
__global__ __launch_bounds__(256)
void cvt_kernel(const float* __restrict__ x,
                const float* __restrict__ wq, const float* __restrict__ wk,
                const float* __restrict__ wv, const float* __restrict__ wo,
                ushort_t* __restrict__ xb,
                ushort_t* __restrict__ wqkvt, ushort_t* __restrict__ wot)
{
    __shared__ float T[32][33];
    const int bid = blockIdx.x;
    if (bid < 1024) {
        int off = (bid * 256 + threadIdx.x) * 8;
        float4 a = *(const float4*)&x[off];
        float4 b = *(const float4*)&x[off + 4];
        ushort_t t[8];
        t[0] = f2bf(a.x); t[1] = f2bf(a.y); t[2] = f2bf(a.z); t[3] = f2bf(a.w);
        t[4] = f2bf(b.x); t[5] = f2bf(b.y); t[6] = f2bf(b.z); t[7] = f2bf(b.w);
        *(uint4*)&xb[off] = *(const uint4*)t;
        return;
    }
    const int r = bid - 1024;
    const int z = r >> 8;
    const int tile = r & 255;
    const float* s = (z == 0) ? wq : (z == 1) ? wk : (z == 2) ? wv : wo;
    ushort_t*    d = (z < 3) ? (wqkvt + (size_t)z * 512 * 512) : wot;
    const int k0 = (tile & 15) * 32;
    const int n0 = (tile >> 4) * 32;
    {
        const int kk = threadIdx.x >> 3;
        const int n4 = (threadIdx.x & 7) * 4;
        float4 v = *(const float4*)&s[(size_t)(k0 + kk) * 512 + n0 + n4];
        T[kk][n4 + 0] = v.x; T[kk][n4 + 1] = v.y;
        T[kk][n4 + 2] = v.z; T[kk][n4 + 3] = v.w;
    }
    __syncthreads();
    {
        const int nn = threadIdx.x >> 3;
        const int k4 = (threadIdx.x & 7) * 4;
        ushort4 o;
        o.x = f2bf(T[k4 + 0][nn]); o.y = f2bf(T[k4 + 1][nn]);
        o.z = f2bf(T[k4 + 2][nn]); o.w = f2bf(T[k4 + 3][nn]);
        *(ushort4*)&d[(size_t)(n0 + nn) * 512 + k0 + k4] = o;
    }
}

// ---------------------------------------------------------------------------
// QKV GEMM (R7 version, proven): 128x64 tile, BK=64, gload_lds(16B),
// chunk-rotated LDS (conflict-free frag reads), fused N=1536.
// ---------------------------------------------------------------------------
#define QM 128
#define QN 64
#define QKS 64

__global__ __launch_bounds__(256)
void gemm_qkv(const ushort_t* __restrict__ A, const ushort_t* __restrict__ Bw,
              ushort_t* __restrict__ q, ushort_t* __restrict__ k,
              ushort_t* __restrict__ vt)
{
    __shared__ ushort_t As[QM * QKS];   // 16 KB: granules 0..1023
    __shared__ ushort_t Bs[QN * QKS];   // 8 KB:  granules 0..511

    const int tid  = threadIdx.x;
    const int wave = tid >> 6;
    const int lane = tid & 63;
    const int quad = lane >> 4;
    const int l15  = lane & 15;
    const int wr   = wave >> 1;
    const int wc   = wave & 1;
    const int bm   = blockIdx.y * QM;
    const int bn   = blockIdx.x * QN;

    const int lr = lane >> 3;
    const int lc = lane & 7;

    const ushort_t* ap[4];
#pragma unroll
    for (int j = 0; j < 4; ++j) {
        const int row = wave * 32 + j * 8 + lr;
        const int c   = (lc - row) & 7;
        ap[j] = &A[(size_t)(bm + row) * DD + c * 8];
    }
    const ushort_t* bp[2];
#pragma unroll
    for (int j = 0; j < 2; ++j) {
        const int row = wave * 16 + j * 8 + lr;
        const int c   = (lc - row) & 7;
        bp[j] = &Bw[(size_t)(bn + row) * DD + c * 8];
    }
    ushort_t* lA0 = &As[(size_t)(wave * 256 +   0) * 8];
    ushort_t* lA1 = &As[(size_t)(wave * 256 +  64) * 8];
    ushort_t* lA2 = &As[(size_t)(wave * 256 + 128) * 8];
    ushort_t* lA3 = &As[(size_t)(wave * 256 + 192) * 8];
    ushort_t* lB0 = &Bs[(size_t)(wave * 128 +  0) * 8];
    ushort_t* lB1 = &Bs[(size_t)(wave * 128 + 64) * 8];

    floatx4 acc[4][2];
#pragma unroll
    for (int i = 0; i < 4; ++i)
#pragma unroll
        for (int j = 0; j < 2; ++j) acc[i][j] = (floatx4){0.f, 0.f, 0.f, 0.f};

#pragma unroll
    for (int k0 = 0; k0 < DD; k0 += QKS) {
        __syncthreads();
        gload16(lA0, ap[0] + k0);
        gload16(lA1, ap[1] + k0);
        gload16(lA2, ap[2] + k0);
        gload16(lA3, ap[3] + k0);
        gload16(lB0, bp[0] + k0);
        gload16(lB1, bp[1] + k0);
        __syncthreads();

#pragma unroll
        for (int kk = 0; kk < 2; ++kk) {
            short8 af[4], bfr[2];
#pragma unroll
            for (int mt = 0; mt < 4; ++mt) {
                const int row = wr * 64 + mt * 16 + l15;
                af[mt] = *(const short8*)
                    &As[((row << 3) + ((kk * 4 + quad + row) & 7)) * 8];
            }
#pragma unroll
            for (int nt = 0; nt < 2; ++nt) {
                const int row = wc * 32 + nt * 16 + l15;
                bfr[nt] = *(const short8*)
                    &Bs[((row << 3) + ((kk * 4 + quad + row) & 7)) * 8];
            }
#pragma unroll
            for (int mt = 0; mt < 4; ++mt)
#pragma unroll
                for (int nt = 0; nt < 2; ++nt)
                    acc[mt][nt] = __builtin_amdgcn_mfma_f32_16x16x32_bf16(
                        af[mt], bfr[nt], acc[mt][nt], 0, 0, 0);
        }
    }

    const int z = bn >> 9;   // 0=Q, 1=K, 2=V (uniform per block)
    if (z == 2) {
#pragma unroll
        for (int mt = 0; mt < 4; ++mt) {
            const int m0 = bm + wr * 64 + mt * 16 + quad * 4;
            const int b  = m0 >> 11;
            const int t0 = m0 & 2047;
#pragma unroll
            for (int nt = 0; nt < 2; ++nt) {
                const int n  = bn + wc * 32 + nt * 16 + l15 - 1024;
                const int h  = n >> 6, dd = n & 63;
                ushort4 o;
                o.x = f2bf(acc[mt][nt][0]); o.y = f2bf(acc[mt][nt][1]);
                o.z = f2bf(acc[mt][nt][2]); o.w = f2bf(acc[mt][nt][3]);
                *(ushort4*)&vt[((size_t)((b * 8 + h) * 64 + dd)) * 2048 + t0] = o;
            }
        }
        return;
    }
    ushort_t* O = (z == 0) ? q : k;
    const int nb = bn - z * 512;
#pragma unroll
    for (int mt = 0; mt < 4; ++mt) {
#pragma unroll
        for (int nt = 0; nt < 2; ++nt) {
            const int n = nb + wc * 32 + nt * 16 + l15;
#pragma unroll
            for (int reg = 0; reg < 4; ++reg) {
                const int m = bm + wr * 64 + mt * 16 + quad * 4 + reg;
                O[(size_t)m * 512 + n] = f2bf(acc[mt][nt][reg]);
            }
        }
    }
}

// ---------------------------------------------------------------------------
// Projection GEMM (R7 version, proven): 64x64, BK=64, gload_lds staging,
// chunk-rotated LDS layout.
// ---------------------------------------------------------------------------
__global__ __launch_bounds__(256)
void gemm_proj(const ushort_t* __restrict__ A, const ushort_t* __restrict__ Bw,
               float* __restrict__ O, const float* __restrict__ bias)
{
    __shared__ ushort_t As[64 * 64];
    __shared__ ushort_t Bs[64 * 64];

    const int tid  = threadIdx.x;
    const int wave = tid >> 6;
    const int lane = tid & 63;
    const int quad = lane >> 4;
    const int l15  = lane & 15;
    const int wr   = wave >> 1;
    const int wc   = wave & 1;
    const int bm   = blockIdx.y * 64;
    const int bn   = blockIdx.x * 64;

    const int lr = lane >> 3;
    const int lc = lane & 7;

    const ushort_t* ap[2];
    const ushort_t* bp[2];
#pragma unroll
    for (int j = 0; j < 2; ++j) {
        const int row = wave * 16 + j * 8 + lr;
        const int c   = (lc - row) & 7;
        ap[j] = &A[(size_t)(bm + row) * INNER + c * 8];
        bp[j] = &Bw[(size_t)(bn + row) * INNER + c * 8];
    }
    ushort_t* lA0 = &As[(size_t)(wave * 128 +  0) * 8];
    ushort_t* lA1 = &As[(size_t)(wave * 128 + 64) * 8];
    ushort_t* lB0 = &Bs[(size_t)(wave * 128 +  0) * 8];
    ushort_t* lB1 = &Bs[(size_t)(wave * 128 + 64) * 8];

    floatx4 acc[2][2];
#pragma unroll
    for (int i = 0; i < 2; ++i)
#pragma unroll
        for (int j = 0; j < 2; ++j) acc[i][j] = (floatx4){0.f, 0.f, 0.f, 0.f};

#pragma unroll
    for (int k0 = 0; k0 < INNER; k0 += 64) {
        __syncthreads();
        gload16(lA0, ap[0] + k0);
        gload16(lA1, ap[1] + k0);
        gload16(lB0, bp[0] + k0);
        gload16(lB1, bp[1] + k0);
        __syncthreads();

#pragma unroll
        for (int kk = 0; kk < 2; ++kk) {
            short8 af[2], bfr[2];
#pragma unroll
            for (int mt = 0; mt < 2; ++mt) {
                const int row = wr * 32 + mt * 16 + l15;
                af[mt] = *(const short8*)
                    &As[((row << 3) + ((kk * 4 + quad + row) & 7)) * 8];
            }
#pragma unroll
            for (int nt = 0; nt < 2; ++nt) {
                const int row = wc * 32 + nt * 16 + l15;
                bfr[nt] = *(const short8*)
                    &Bs[((row << 3) + ((kk * 4 + quad + row) & 7)) * 8];
            }
#pragma unroll
            for (int mt = 0; mt < 2; ++mt)
#pragma unroll
                for (int nt = 0; nt < 2; ++nt)
                    acc[mt][nt] = __builtin_amdgcn_mfma_f32_16x16x32_bf16(
                        af[mt], bfr[nt], acc[mt][nt], 0, 0, 0);
        }
    }

    float bv[2];
#pragma unroll
    for (int nt = 0; nt < 2; ++nt)
        bv[nt] = bias[bn + wc * 32 + nt * 16 + l15];
#pragma unroll
    for (int mt = 0; mt < 2; ++mt) {
#pragma unroll
        for (int nt = 0; nt < 2; ++nt) {
            const int n = bn + wc * 32 + nt * 16 + l15;
#pragma unroll
            for (int reg = 0; reg < 4; ++reg) {
                const int m = bm + wr * 32 + mt * 16 + quad * 4 + reg;
                O[(size_t)m * 512 + n] = acc[mt][nt][reg] + bv[nt];
            }
        }
    }
}

// ---------------------------------------------------------------------------
// MFMA flash attention, chunked K-split (chunk=8, heavy-first), K AND V in
// LDS (R7 structure). K/V prefetch for tile kt+1 is issued AFTER the second
// barrier (top of compute) instead of before it. hipcc drains vmcnt(0)
// before every s_barrier, so the old placement exposed the full global-load
// latency at bar2 every iteration; the new placement gives the loads the
// whole QK+softmax+PV phase to complete before next bar1.
// ---------------------------------------------------------------------------
#define PAD 72
#define MFIX 10.0f

__global__ __launch_bounds__(256)
void attn_mfma(const ushort_t* __restrict__ Qg,
               const ushort_t* __restrict__ Kg,
               const ushort_t* __restrict__ Vtg,
               const float* __restrict__ lagw,
               ushort_t* __restrict__ Opart,
               float* __restrict__ Lpart,
               ushort_t* __restrict__ ao)
{
    __shared__ ushort_t Ks[64 * 8 * 8];
    __shared__ ushort_t Vts[64 * 8 * 8];
    __shared__ ushort_t Pl[4][16][PAD];

    const int tid  = threadIdx.x;
    const int wave = tid >> 6;
    const int lane = tid & 63;
    const int quad = lane >> 4;
    const int l15  = lane & 15;

    // heavy-first chunk decode: f = rank*16 + bh; rank rr in [0,80)
    const int f  = blockIdx.x;           // 0..1279
    const int rr = f >> 4;
    const int bh = f & 15;
    int qt, ci;
    if (rr < 32)      { qt = 31 - (rr >> 2); ci = rr & 3; }
    else if (rr < 56) { const int t = rr - 32; qt = 23 - t / 3; ci = t % 3; }
    else if (rr < 72) { const int t = rr - 56; qt = 15 - (t >> 1); ci = t & 1; }
    else              { qt = 79 - rr; ci = 0; }
    const int lo = ci * 8;
    const int hi = min(lo + 8, qt + 1);
    const int nch = (qt >> 3) + 1;

    const int b  = bh >> 3;
    const int h  = bh & 7;
    const int i0 = qt * 64;

    float lagb[MAXLAG + 1];
    {
        float mx = -1e30f;
#pragma unroll
        for (int l = 0; l <= MAXLAG; ++l) {
            lagb[l] = lagw[h * (MAXLAG + 1) + l];
            mx = fmaxf(mx, lagb[l]);
        }
        float s = 0.f;
#pragma unroll
        for (int l = 0; l <= MAXLAG; ++l) { lagb[l] = __expf(lagb[l] - mx); s += lagb[l]; }
        float inv = 1.f / s;
#pragma unroll
        for (int l = 0; l <= MAXLAG; ++l) lagb[l] = lagb[l] * inv - MFIX;
    }
    const float c1  = 0.125f;
    const float c2f = lagb[MAXLAG];

    short8 qf0, qf1;
    {
        const ushort_t* qbase =
            Qg + ((size_t)(b * TT + i0 + wave * 16 + l15)) * INNER + h * DH;
        qf0 = *(const short8*)(qbase + quad * 8);
        qf1 = *(const short8*)(qbase + 32 + quad * 8);
    }

    floatx4 oacc[4];
    float lsum[4] = {0.f, 0.f, 0.f, 0.f};
#pragma unroll
    for (int cb = 0; cb < 4; ++cb) oacc[cb] = (floatx4){0.f, 0.f, 0.f, 0.f};

    const int ibase = i0 + wave * 16 + quad * 4;

    const int srow = tid >> 3;
    const int sc   = tid & 7;
    const ushort_t* Kp0 = Kg + ((size_t)(b * TT) + srow) * INNER + h * DH + sc * 8;
    const ushort_t* Kp1 = Kp0 + (size_t)32 * INNER;
    const ushort_t* Vp0 = Vtg + ((size_t)(bh * 64 + srow)) * 2048 + sc * 8;
    const ushort_t* Vp1 = Vp0 + (size_t)32 * 2048;
    const int slot = (sc + srow) & 7;
    const int kdst0 = ((srow << 3) + slot) << 3;
    const int kdst1 = (((srow + 32) << 3) + slot) << 3;

    uint4 pk0, pk1, pv0, pv1;
    {
        const size_t koff = (size_t)(lo * 64) * INNER;
        pk0 = *(const uint4*)(Kp0 + koff);
        pk1 = *(const uint4*)(Kp1 + koff);
        pv0 = *(const uint4*)(Vp0 + lo * 64);
        pv1 = *(const uint4*)(Vp1 + lo * 64);
    }

    for (int kt = lo; kt < hi; ++kt) {
        __syncthreads();                 // bar1: prev compute done with LDS
        *(uint4*)&Ks[kdst0]  = pk0;
        *(uint4*)&Ks[kdst1]  = pk1;
        *(uint4*)&Vts[kdst0] = pv0;
        *(uint4*)&Vts[kdst1] = pv1;
        __syncthreads();                 // bar2: stage visible (no loads pending)

        // Prefetch kt+1 AFTER bar2: latency hides under the whole compute
        // phase; next bar1's vmcnt(0) is the consumer-side wait.
        if (kt + 1 < hi) {
            const size_t koff = (size_t)((kt + 1) * 64) * INNER;
            pk0 = *(const uint4*)(Kp0 + koff);
            pk1 = *(const uint4*)(Kp1 + koff);
            pv0 = *(const uint4*)(Vp0 + (kt + 1) * 64);
            pv1 = *(const uint4*)(Vp1 + (kt + 1) * 64);
        }

        const int j0 = kt * 64;

        floatx4 sacc[4];
#pragma unroll
        for (int cb = 0; cb < 4; ++cb) {
            const int key = cb * 16 + l15;
            short8 kf0 = *(const short8*)&Ks[((key << 3) + ((quad + key) & 7)) << 3];
            short8 kf1 = *(const short8*)&Ks[((key << 3) + ((quad + 4 + key) & 7)) << 3];
            floatx4 zf = (floatx4){0.f, 0.f, 0.f, 0.f};
            zf = __builtin_amdgcn_mfma_f32_16x16x32_bf16(qf0, kf0, zf, 0, 0, 0);
            zf = __builtin_amdgcn_mfma_f32_16x16x32_bf16(qf1, kf1, zf, 0, 0, 0);
            sacc[cb] = zf;
        }

        float p[4][4];
        if (i0 + wave * 16 - (j0 + 63) >= MAXLAG) {
#pragma unroll
            for (int cb = 0; cb < 4; ++cb)
#pragma unroll
                for (int reg = 0; reg < 4; ++reg)
                    p[cb][reg] = __expf(fmaf(sacc[cb][reg], c1, c2f));
        } else {
#pragma unroll
            for (int cb = 0; cb < 4; ++cb) {
                const int j = j0 + cb * 16 + l15;
#pragma unroll
                for (int reg = 0; reg < 4; ++reg) {
                    const int lag = (ibase + reg) - j;
                    float bias = (lag <= 0) ? lagb[0]
                               : (lag == 1) ? lagb[1]
                               : (lag == 2) ? lagb[2]
                               : (lag == 3) ? lagb[3]
                               : (lag == 4) ? lagb[4] : lagb[5];
                    float e = __expf(fmaf(sacc[cb][reg], c1, bias));
                    p[cb][reg] = (lag < 0) ? 0.f : e;
                }
            }
        }
#pragma unroll
        for (int cb = 0; cb < 4; ++cb)
#pragma unroll
            for (int reg = 0; reg < 4; ++reg)
                lsum[reg] += p[cb][reg];

#pragma unroll
        for (int cb = 0; cb < 4; ++cb)
#pragma unroll
            for (int reg = 0; reg < 4; ++reg)
                Pl[wave][quad * 4 + reg][cb * 16 + l15] = f2bf(p[cb][reg]);

        short8 pf0 = *(const short8*)&Pl[wave][l15][quad * 8];
        short8 pf1 = *(const short8*)&Pl[wave][l15][32 + quad * 8];

#pragma unroll
        for (int cb = 0; cb < 4; ++cb) {
            const int dd = cb * 16 + l15;
            short8 vf0 = *(const short8*)&Vts[((dd << 3) + ((quad + dd) & 7)) << 3];
            short8 vf1 = *(const short8*)&Vts[((dd << 3) + ((quad + 4 + dd) & 7)) << 3];
            oacc[cb] = __builtin_amdgcn_mfma_f32_16x16x32_bf16(pf0, vf0, oacc[cb], 0, 0, 0);
            oacc[cb] = __builtin_amdgcn_mfma_f32_16x16x32_bf16(pf1, vf1, oacc[cb], 0, 0, 0);
        }
    }

#pragma unroll
    for (int reg = 0; reg < 4; ++reg) {
        lsum[reg] += __shfl_xor(lsum[reg], 1);
        lsum[reg] += __shfl_xor(lsum[reg], 2);
        lsum[reg] += __shfl_xor(lsum[reg], 4);
        lsum[reg] += __shfl_xor(lsum[reg], 8);
    }

    if (nch == 1) {
        // single-chunk group (qt<8): normalize + write final output directly
#pragma unroll
        for (int reg = 0; reg < 4; ++reg) {
            const int row = ibase + reg;
            const float inv = 1.f / lsum[reg];
            ushort_t* dst = &ao[((size_t)(b * TT + row)) * INNER + h * DH];
#pragma unroll
            for (int cb = 0; cb < 4; ++cb)
                dst[cb * 16 + l15] = f2bf(oacc[cb][reg] * inv);
        }
        return;
    }

    // multi-chunk: write unnormalized partials into slot ci
#pragma unroll
    for (int reg = 0; reg < 4; ++reg) {
        const int row = ibase + reg;
        const size_t obase = ((size_t)(ci * 16 + bh) * TT + row) * 64;
#pragma unroll
        for (int cb = 0; cb < 4; ++cb)
            Opart[obase + cb * 16 + l15] = f2bf(oacc[cb][reg]);
        if (l15 == 0)
            Lpart[(size_t)(ci * 16 + bh) * TT + row] = lsum[reg];
    }
}

// ---------------------------------------------------------------------------
// Combine up to 4 chunk partials -> ao bf16 [b*T+i][h*64+d], rows i>=512
// only (qt>=8 <=> nch>=2; qt<8 rows were written inline by attn_mfma).
// ---------------------------------------------------------------------------
#define CMB_ROWS (TT - 512)
#define CMB_UNITS (16 * CMB_ROWS * 16)

__global__ __launch_bounds__(256)
void combine_kernel(const ushort_t* __restrict__ Opart,
                    const float* __restrict__ Lpart,
                    ushort_t* __restrict__ ao)
{
    int u = blockIdx.x * 256 + threadIdx.x;
    const int bh  = u / (CMB_ROWS * 16);
    const int rem = u - bh * (CMB_ROWS * 16);
    const int i   = 512 + (rem >> 4);
    const int d   = (rem & 15) * 4;
    const int b   = bh >> 3;
    const int h   = bh & 7;
    const int nch = ((i >> 6) >> 3) + 1;

    float s0 = 0.f, s1 = 0.f, s2 = 0.f, s3 = 0.f, l = 0.f;
    for (int ci = 0; ci < nch; ++ci) {
        const size_t p = ((size_t)(ci * 16 + bh) * TT + i) * 64 + d;
        ushort4 a = *(const ushort4*)&Opart[p];
        s0 += bf2f(a.x); s1 += bf2f(a.y); s2 += bf2f(a.z); s3 += bf2f(a.w);
        l  += Lpart[(size_t)(ci * 16 + bh) * TT + i];
    }
    const float inv = 1.f / l;
    ushort4 o;
    o.x = f2bf(s0 * inv);
    o.y = f2bf(s1 * inv);
    o.z = f2bf(s2 * inv);
    o.w = f2bf(s3 * inv);
    *(ushort4*)&ao[((size_t)(b * TT + i)) * INNER + h * DH + d] = o;
}

// ---------------------------------------------------------------------------
extern "C" void kernel_launch(void* const* d_in, const int* in_sizes, int n_in,
                              void* d_out, int out_size, void* d_ws, size_t ws_size,
                              hipStream_t stream)
{
    const float* x  = (const float*)d_in[0];
    const float* Wq = (const float*)d_in[1];
    const float* Wk = (const float*)d_in[2];
    const float* Wv = (const float*)d_in[3];
    const float* Wo = (const float*)d_in[4];
    const float* bo = (const float*)d_in[5];
    const float* lw = (const float*)d_in[6];
    float* out = (float*)d_out;

    const size_t SZ  = (size_t)BB * TT * INNER;  // 2M elements
    const size_t NWE = (size_t)DD * INNER;       // 256K per weight
    ushort_t* xb    = (ushort_t*)d_ws;
    ushort_t* wqkvt = xb + SZ;                   // fused [1536][512]
    ushort_t* wot   = wqkvt + 3 * NWE;
    ushort_t* q     = wot + NWE;
    ushort_t* k     = q + SZ;
    ushort_t* vt    = k + SZ;                    // V TRANSPOSED [bh][d][t]
    ushort_t* opart = vt + SZ;                   // 4 slots * 16*TT*64
    float*    lpart = (float*)(opart + 4 * (size_t)16 * TT * 64);
    ushort_t* ao    = xb;                        // alias: xb dead after QKV

    cvt_kernel<<<2048, 256, 0, stream>>>(x, Wq, Wk, Wv, Wo, xb, wqkvt, wot);

    dim3 gQKV(3 * INNER / QN, (BB * TT) / QM);   // (24, 32) = 768 blocks
    gemm_qkv<<<gQKV, 256, 0, stream>>>(xb, wqkvt, q, k, vt);

    attn_mfma<<<1280, 256, 0, stream>>>(q, k, vt, lw, opart, lpart, ao);

    combine_kernel<<<CMB_UNITS / 256, 256, 0, stream>>>(opart, lpart, ao);

    dim3 gPRJ(DD / 64, (BB * TT) / 64);          // (8, 64) = 512 blocks
    gemm_proj<<<gPRJ, 256, 0, stream>>>(ao, wot, out, bo);
}